// Round 3
// baseline (948.430 us; speedup 1.0000x reference)
//
#include <hip/hip_runtime.h>

#define N_NODES 100000
#define NPAD    100096      // 782 * 128
#define NTILES  782
#define G_GRAPHS 256
#define IN_F 162
#define HID 128
#define R_REL 5
#define L_LAYERS 2
#define M5 (R_REL * N_NODES)
#define KSEG0 192           // logical K width of layer-0 segments (6 k-steps)
#define PSEG0 168           // physical packed width of layer-0 Z segments
#define SZ0   (5 * PSEG0)   // 840 : Z0 row stride
#define SZ1   (5 * HID)     // 640 : Z1 row stride
#define KC0   (6 * KSEG0)   // 1152 : logical K of layer-0 GEMM (W layout)
#define KC1   (6 * HID)     // 768  : logical K of layer-1/2 GEMM

typedef __attribute__((ext_vector_type(8))) short bf16x8;
typedef __attribute__((ext_vector_type(4))) float f32x4;

__device__ __forceinline__ short f2bf(float f) {
    union { float f; unsigned u; } v; v.f = f;
    unsigned r = (v.u + 0x7fffu + ((v.u >> 16) & 1u)) >> 16;
    return (short)r;
}
__device__ __forceinline__ float bf2f(unsigned short u) {
    union { unsigned u; float f; } v; v.u = ((unsigned)u) << 16;
    return v.f;
}

// ---------------- CSR build, keyed by (relation, dst) ----------------
__global__ void k_count(const int* e0, const int* e1, const int* e2,
                        const int* e3, const int* e4, int* cnt, int E) {
    int gid = blockIdx.x * 256 + threadIdx.x;
    if (gid >= R_REL * E) return;
    int r = gid / E, e = gid - r * E;
    const int* ei = (r == 0) ? e0 : (r == 1) ? e1 : (r == 2) ? e2 : (r == 3) ? e3 : e4;
    atomicAdd(&cnt[r * N_NODES + ei[E + e]], 1);
}

__global__ __launch_bounds__(256) void k_scan1(const int* __restrict__ cnt,
                                               int* __restrict__ off, int* __restrict__ bsum) {
    __shared__ int ts[256];
    int t = threadIdx.x;
    int base = blockIdx.x * 1024 + t * 4;
    int v[4];
    #pragma unroll
    for (int j = 0; j < 4; j++) v[j] = (base + j < M5) ? cnt[base + j] : 0;
    int tsum = v[0] + v[1] + v[2] + v[3];
    ts[t] = tsum; __syncthreads();
    for (int o = 1; o < 256; o <<= 1) {
        int x = (t >= o) ? ts[t - o] : 0;
        __syncthreads();
        ts[t] += x;
        __syncthreads();
    }
    if (t == 255) bsum[blockIdx.x] = ts[255];
    int run = ts[t] - tsum;
    #pragma unroll
    for (int j = 0; j < 4; j++) { if (base + j < M5) off[base + j] = run; run += v[j]; }
}

__global__ __launch_bounds__(512) void k_scan2(int* bsum, int nblk) {
    __shared__ int ts[512];
    int t = threadIdx.x;
    int v = (t < nblk) ? bsum[t] : 0;
    ts[t] = v; __syncthreads();
    for (int o = 1; o < 512; o <<= 1) {
        int x = (t >= o) ? ts[t - o] : 0;
        __syncthreads();
        ts[t] += x;
        __syncthreads();
    }
    if (t < nblk) bsum[t] = ts[t] - v;   // exclusive
}

__global__ void k_scan3(const int* __restrict__ off, const int* __restrict__ bsum,
                        int* __restrict__ mstart, int* __restrict__ mcur,
                        const int* __restrict__ cnt, float* __restrict__ invc) {
    int i = blockIdx.x * 256 + threadIdx.x;
    if (i >= M5) return;
    int o = off[i] + bsum[i >> 10];
    mstart[i] = o;
    mcur[i] = o;
    int c = cnt[i];
    invc[i] = 1.0f / (float)max(c, 1);
    if (i == M5 - 1) mstart[M5] = o + c;
}

__global__ void k_fill(const int* e0, const int* e1, const int* e2,
                       const int* e3, const int* e4, int* mcur,
                       int* __restrict__ mrec, int E) {
    int gid = blockIdx.x * 256 + threadIdx.x;
    if (gid >= R_REL * E) return;
    int r = gid / E, e = gid - r * E;
    const int* ei = (r == 0) ? e0 : (r == 1) ? e1 : (r == 2) ? e2 : (r == 3) ? e3 : e4;
    int src = ei[e], dst = ei[E + e];
    int pos = atomicAdd(&mcur[r * N_NODES + dst], 1);
    mrec[pos] = src;
}

// ---------------- X fp32 -> bf16, padded [NPAD][192] ----------------
__global__ void k_castX(const float* __restrict__ X, unsigned short* __restrict__ Xb) {
    int gid = blockIdx.x * 256 + threadIdx.x;
    if (gid >= NPAD * KSEG0) return;
    int row = gid / KSEG0, k = gid - row * KSEG0;
    float v = (row < N_NODES && k < IN_F) ? X[(size_t)row * IN_F + k] : 0.f;
    Xb[gid] = (unsigned short)f2bf(v);
}

// ---------------- weight transpose: Wt[col][KCAT] with seg-concat K ----------------
__global__ void k_tw0(const float* __restrict__ root0, const float* __restrict__ W0,
                      short* __restrict__ out) {
    int gid = blockIdx.x * 256 + threadIdx.x;   // 128 * 1152
    if (gid >= 128 * KC0) return;
    int col = gid / KC0;
    int kk = gid - col * KC0;
    int chunk = kk / KSEG0, k = kk - chunk * KSEG0;
    float v = 0.f;
    if (k < IN_F)
        v = (chunk == 0) ? root0[k * HID + col]
                         : W0[((size_t)(chunk - 1) * IN_F + k) * HID + col];
    out[gid] = f2bf(v);
}

__global__ void k_twl(const float* __restrict__ rootl, const float* __restrict__ Wl,
                      short* __restrict__ out) {
    int gid = blockIdx.x * 256 + threadIdx.x;   // 2 * 128 * 768
    if (gid >= L_LAYERS * 128 * KC1) return;
    int l = gid / (128 * KC1);
    int rem = gid - l * 128 * KC1;
    int col = rem / KC1;
    int kk = rem - col * KC1;
    int chunk = kk / HID, k = kk - chunk * HID;
    float v = (chunk == 0) ? rootl[((size_t)l * HID + k) * HID + col]
                           : Wl[(((size_t)l * R_REL + (chunk - 1)) * HID + k) * HID + col];
    out[gid] = f2bf(v);
}

// ---------------- aggregate-first: Z_r[d] = (1/c) * sum H[src] ----------------
// One wave per (r,d). L0: H = Xb [NPAD][192], Z row stride 840, packed seg width 168
// (cols 162..167 are zero-sums; cols 168..191 of the logical 192 are never stored —
// their weight columns are zero). Layers: H = h [NPAD][128], Z stride 640.
template<bool L0>
__global__ __launch_bounds__(256)
void aggregate_seg(const unsigned short* __restrict__ H, unsigned short* __restrict__ Z,
                   const int* __restrict__ mstart, const int* __restrict__ mrec,
                   const float* __restrict__ invc) {
    constexpr int HS = L0 ? KSEG0 : HID;
    constexpr int ZS = L0 ? SZ0 : SZ1;
    constexpr int PS = L0 ? PSEG0 : HID;
    int wid = (blockIdx.x * 256 + threadIdx.x) >> 6;
    int lane = threadIdx.x & 63;
    if (wid >= M5) return;
    int r = wid / N_NODES;
    int d = wid - r * N_NODES;
    int s = mstart[wid], e = mstart[wid + 1];
    float s0 = 0.f, s1 = 0.f, s2 = 0.f, s3 = 0.f;
    for (int j = s; j < e; j++) {
        int src = mrec[j];                       // wave-uniform broadcast load
        const unsigned short* row = H + (size_t)src * HS;
        unsigned v = *(const unsigned*)(row + lane * 2);
        s0 += bf2f((unsigned short)(v & 0xffff));
        s1 += bf2f((unsigned short)(v >> 16));
        if constexpr (L0) {
            if (lane < 32) {
                unsigned v2 = *(const unsigned*)(row + 128 + lane * 2);
                s2 += bf2f((unsigned short)(v2 & 0xffff));
                s3 += bf2f((unsigned short)(v2 >> 16));
            }
        }
    }
    float w = invc[wid];
    unsigned short* dst = Z + (size_t)d * ZS + (size_t)r * PS;
    unsigned lo = (unsigned short)f2bf(s0 * w);
    unsigned hi = (unsigned short)f2bf(s1 * w);
    *(unsigned*)(dst + lane * 2) = lo | (hi << 16);
    if constexpr (L0) {
        if (lane < 20) {                         // cols 128..167 (162..167 are zero)
            unsigned lo2 = (unsigned short)f2bf(s2 * w);
            unsigned hi2 = (unsigned short)f2bf(s3 * w);
            *(unsigned*)(dst + 128 + lane * 2) = lo2 | (hi2 << 16);
        }
    }
}

// ---------------- segmented-K MFMA GEMM, fused bias+ReLU epilogue ----------------
// h[row][0:128] = relu( [A0 | Z_0..Z_4] @ Wt^T + bias ). seg0 (KS0 k-steps) reads A0
// at stride SA0; Z segs (KSZ logical k-steps each) read Z at stride SZ, packed seg
// width PSEG (<= 32*KSZ; spill cols have zero weights). 128x128 tile, 4 waves 2x2,
// register double-buffered fragments, B direct from global (L2-resident).
template<int KS0, int KSZ, int PSEG, int SA0, int SZ>
__global__ __launch_bounds__(256)
void gemm_seg(const unsigned short* __restrict__ A0, const unsigned short* __restrict__ Z,
              const short* __restrict__ Wt, const float* __restrict__ bias,
              unsigned short* __restrict__ Hout) {
    constexpr int TS = KS0 + 5 * KSZ;
    constexpr int KCAT = TS * 32;
    constexpr int SE = 136;                     // epilogue LDS row stride (shorts)
    __shared__ short Es[128 * SE];

    const int row0 = blockIdx.x * 128;
    const int tid = threadIdx.x;
    const int lane = tid & 63, wv = tid >> 6;
    const int quad = lane >> 4, l16 = lane & 15;
    const int wr0 = (wv >> 1) * 64, wc0 = (wv & 1) * 64;

    const unsigned short* a0p = A0 + (size_t)(row0 + wr0 + l16) * SA0 + quad * 8;
    const unsigned short* zp  = Z  + (size_t)(row0 + wr0 + l16) * SZ  + quad * 8;
    const short* Bp = Wt + (size_t)(wc0 + l16) * KCAT + quad * 8;

    auto ldA = [&](int t, int i) -> bf16x8 {
        if (t < KS0)
            return *(const bf16x8*)(a0p + (size_t)i * 16 * SA0 + t * 32);
        int sg = (t - KS0) / KSZ, k = (t - KS0) - sg * KSZ;
        return *(const bf16x8*)(zp + (size_t)i * 16 * SZ + sg * PSEG + k * 32);
    };
    auto ldB = [&](int t, int j) -> bf16x8 {
        return *(const bf16x8*)(Bp + (size_t)j * 16 * KCAT + t * 32);
    };

    bf16x8 ac[4], bc[4];
    #pragma unroll
    for (int i = 0; i < 4; i++) { ac[i] = ldA(0, i); bc[i] = ldB(0, i); }

    f32x4 acc[4][4];
    #pragma unroll
    for (int i = 0; i < 4; i++)
        #pragma unroll
        for (int j = 0; j < 4; j++) acc[i][j] = (f32x4){0.f, 0.f, 0.f, 0.f};

    #pragma unroll
    for (int t = 0; t < TS; t++) {
        bf16x8 an[4], bn[4];
        if (t + 1 < TS) {
            #pragma unroll
            for (int i = 0; i < 4; i++) { an[i] = ldA(t + 1, i); bn[i] = ldB(t + 1, i); }
        }
        #pragma unroll
        for (int i = 0; i < 4; i++)
            #pragma unroll
            for (int j = 0; j < 4; j++)
                acc[i][j] = __builtin_amdgcn_mfma_f32_16x16x32_bf16(ac[i], bc[j], acc[i][j], 0, 0, 0);
        if (t + 1 < TS) {
            #pragma unroll
            for (int i = 0; i < 4; i++) { ac[i] = an[i]; bc[i] = bn[i]; }
        }
    }

    // fused bias + relu -> LDS -> coalesced bf16x8 stores
    float bj[4];
    #pragma unroll
    for (int j = 0; j < 4; j++) bj[j] = bias[wc0 + j * 16 + l16];
    #pragma unroll
    for (int i = 0; i < 4; i++)
        #pragma unroll
        for (int j = 0; j < 4; j++)
            #pragma unroll
            for (int reg = 0; reg < 4; reg++)
                Es[(wr0 + i * 16 + quad * 4 + reg) * SE + wc0 + j * 16 + l16] =
                    f2bf(fmaxf(acc[i][j][reg] + bj[j], 0.f));
    __syncthreads();

    #pragma unroll
    for (int s = 0; s < 8; s++) {
        int row = (tid >> 4) + s * 16;
        int col = (tid & 15) * 8;
        bf16x8 v = *(const bf16x8*)&Es[row * SE + col];
        *(bf16x8*)&Hout[(size_t)(row0 + row) * HID + col] = v;
    }
}

// ---------------- readout ----------------
__global__ __launch_bounds__(128)
void k_pool(const unsigned short* __restrict__ h, const int* __restrict__ batch,
            float* __restrict__ pooled) {
    int c = threadIdx.x;
    int start = blockIdx.x * 128;
    if (start >= N_NODES) return;
    int end = min(start + 128, N_NODES);
    int g = batch[start];
    float s = 0.f;
    for (int i = start; i < end; i++) {
        int gi = batch[i];
        if (gi != g) { atomicAdd(&pooled[g * HID + c], s); s = 0.f; g = gi; }
        s += bf2f(h[(size_t)i * HID + c]);
    }
    atomicAdd(&pooled[g * HID + c], s);
}

__device__ int lower_bound_i(const int* a, int n, int v) {
    int lo = 0, hi = n;
    while (lo < hi) {
        int mid = (lo + hi) >> 1;
        if (a[mid] < v) lo = mid + 1; else hi = mid;
    }
    return lo;
}

__global__ __launch_bounds__(128)
void k_mlp(const float* __restrict__ pooled, const int* __restrict__ batch,
           const float* __restrict__ Wc1, const float* __restrict__ bc1,
           const float* __restrict__ Wc2, const float* __restrict__ bc2,
           const float* __restrict__ Wc3, const float* __restrict__ bc3,
           float* __restrict__ out) {
    int g = blockIdx.x;
    int c = threadIdx.x;
    __shared__ int range[2];
    if (c == 0) range[0] = lower_bound_i(batch, N_NODES, g);
    if (c == 1) range[1] = lower_bound_i(batch, N_NODES, g + 1);
    __syncthreads();
    float denom = fmaxf((float)(range[1] - range[0]), 1.0f);
    __shared__ float row[HID], h1[HID], h2[HID];
    row[c] = pooled[g * HID + c] / denom;
    __syncthreads();
    float acc = bc1[c];
    for (int k = 0; k < HID; k++) acc += row[k] * Wc1[k * HID + c];
    h1[c] = fmaxf(acc, 0.f);
    __syncthreads();
    acc = bc2[c];
    for (int k = 0; k < HID; k++) acc += h1[k] * Wc2[k * HID + c];
    h2[c] = fmaxf(acc, 0.f);
    __syncthreads();
    float t = h2[c] * Wc3[c];
    for (int off = 32; off > 0; off >>= 1) t += __shfl_down(t, off, 64);
    __shared__ float part[2];
    if ((c & 63) == 0) part[c >> 6] = t;
    __syncthreads();
    if (c == 0) out[g] = part[0] + part[1] + bc3[0];
}

// ---------------- launcher ----------------
extern "C" void kernel_launch(void* const* d_in, const int* in_sizes, int n_in,
                              void* d_out, int out_size, void* d_ws, size_t ws_size,
                              hipStream_t stream) {
    const float* X     = (const float*)d_in[0];
    const int*   batch = (const int*)d_in[1];
    const int*   e0 = (const int*)d_in[2];
    const int*   e1 = (const int*)d_in[3];
    const int*   e2 = (const int*)d_in[4];
    const int*   e3 = (const int*)d_in[5];
    const int*   e4 = (const int*)d_in[6];
    const float* W0    = (const float*)d_in[7];
    const float* root0 = (const float*)d_in[8];
    const float* b0    = (const float*)d_in[9];
    const float* Wl    = (const float*)d_in[10];
    const float* rootl = (const float*)d_in[11];
    const float* bl    = (const float*)d_in[12];
    const float* Wc1   = (const float*)d_in[13];
    const float* bc1   = (const float*)d_in[14];
    const float* Wc2   = (const float*)d_in[15];
    const float* bc2   = (const float*)d_in[16];
    const float* Wc3   = (const float*)d_in[17];
    const float* bc3   = (const float*)d_in[18];
    const int E = in_sizes[2] / 2;
    const int NE = R_REL * E;

    char* base = (char*)d_ws;
    size_t o = 0;
    auto carve = [&](size_t bytes) -> char* {
        char* p = base + o;
        o = (o + bytes + 255) & ~(size_t)255;
        return p;
    };
    // Peak live set: h1 + Xb + Z0 + misc = 243.4 MB (< round-0's known-good 254.25 MB).
    unsigned short* h1 = (unsigned short*)carve((size_t)NPAD * HID * 2);    // also h3
    unsigned short* Xb = (unsigned short*)carve((size_t)NPAD * KSEG0 * 2);  // also h2
    unsigned short* Z0 = (unsigned short*)carve((size_t)NPAD * SZ0 * 2 + 256); // also Z1
    int*   cnt    = (int*)carve((size_t)M5 * 4);
    float* invc   = (float*)carve((size_t)M5 * 4);
    int*   offsc  = (int*)carve((size_t)M5 * 4);
    int*   mstart = (int*)carve((size_t)(M5 + 1) * 4);
    int*   mrec   = (int*)carve((size_t)NE * 4);
    int*   bsum   = (int*)carve(2048);
    float* pooled = (float*)carve((size_t)G_GRAPHS * HID * 4);
    short* Wt0    = (short*)carve((size_t)128 * KC0 * 2);
    short* Wtl    = (short*)carve((size_t)L_LAYERS * 128 * KC1 * 2);
    int*   mcur   = offsc;                 // offsc dead after k_scan3
    unsigned short* h2 = Xb;               // Xb dead after layer-0 GEMM
    unsigned short* Z1 = Z0;               // Z0 dead after layer-0 GEMM (stride 640 inside)

    // ---- CSR build + casts + weight transposes ----
    hipMemsetAsync(cnt, 0, (size_t)M5 * 4, stream);
    hipMemsetAsync(pooled, 0, (size_t)G_GRAPHS * HID * 4, stream);
    // zero Z0's padded rows (+ spill tail) so the packed-168 spill never reads NaN
    hipMemsetAsync(Z0 + (size_t)N_NODES * SZ0, 0,
                   ((size_t)(NPAD - N_NODES) * SZ0 + 64) * 2, stream);
    int eg = (NE + 255) / 256;
    k_count<<<eg, 256, 0, stream>>>(e0, e1, e2, e3, e4, cnt, E);
    int nblk = (M5 + 1023) / 1024;   // 489
    k_scan1<<<nblk, 256, 0, stream>>>(cnt, offsc, bsum);
    k_scan2<<<1, 512, 0, stream>>>(bsum, nblk);
    k_scan3<<<(M5 + 255) / 256, 256, 0, stream>>>(offsc, bsum, mstart, mcur, cnt, invc);
    k_fill<<<eg, 256, 0, stream>>>(e0, e1, e2, e3, e4, mcur, mrec, E);
    k_castX<<<(NPAD * KSEG0 + 255) / 256, 256, 0, stream>>>(X, Xb);
    k_tw0<<<(128 * KC0 + 255) / 256, 256, 0, stream>>>(root0, W0, Wt0);
    k_twl<<<(L_LAYERS * 128 * KC1 + 255) / 256, 256, 0, stream>>>(rootl, Wl, Wtl);

    const int agrid = (M5 * 64) / 256;   // 125000: one wave per (r,d)

    // ---- layer 0: aggregate Xb -> Z0 (packed 168), K=1152 GEMM -> h1 ----
    aggregate_seg<true><<<agrid, 256, 0, stream>>>(Xb, Z0, mstart, mrec, invc);
    gemm_seg<6, 6, PSEG0, KSEG0, SZ0><<<NTILES, 256, 0, stream>>>(Xb, Z0, Wt0, b0, h1);

    // ---- layer 1: aggregate h1 -> Z1 (stride 640), K=768 GEMM -> h2 (Xb region) ----
    aggregate_seg<false><<<agrid, 256, 0, stream>>>(h1, Z1, mstart, mrec, invc);
    gemm_seg<4, 4, HID, HID, SZ1><<<NTILES, 256, 0, stream>>>(h1, Z1, Wtl, bl, h2);

    // ---- layer 2: aggregate h2 -> Z1, K=768 GEMM -> h3 (h1 region) ----
    aggregate_seg<false><<<agrid, 256, 0, stream>>>(h2, Z1, mstart, mrec, invc);
    gemm_seg<4, 4, HID, HID, SZ1><<<NTILES, 256, 0, stream>>>(h2, Z1, Wtl + (size_t)128 * KC1,
                                                              bl + HID, h1);

    // ---- readout ----
    k_pool<<<(N_NODES + 127) / 128, 128, 0, stream>>>(h1, batch, pooled);
    k_mlp<<<G_GRAPHS, 128, 0, stream>>>(pooled, batch, Wc1, bc1, Wc2, bc2, Wc3, bc3, (float*)d_out);
}

// Round 7
// 829.305 us; speedup vs baseline: 1.1436x; 1.1436x over previous
//
#include <hip/hip_runtime.h>

#define N_NODES 100000
#define NPAD    100096      // 782 * 128
#define NTILES  782
#define G_GRAPHS 256
#define IN_F 162
#define HID 128
#define R_REL 5
#define L_LAYERS 2
#define M5 (R_REL * N_NODES)
#define KSEG0 192           // layer-0 segment width (162 padded to 192)
#define KC0   (6 * KSEG0)   // 1152 : logical K of layer-0 GEMM
#define KC1   (6 * HID)     // 768  : logical K of layer-1/2 GEMM

typedef __attribute__((ext_vector_type(8))) short bf16x8;
typedef __attribute__((ext_vector_type(4))) float f32x4;

__device__ __forceinline__ short f2bf(float f) {
    union { float f; unsigned u; } v; v.f = f;
    unsigned r = (v.u + 0x7fffu + ((v.u >> 16) & 1u)) >> 16;
    return (short)r;
}
__device__ __forceinline__ float bf2f(unsigned short u) {
    union { unsigned u; float f; } v; v.u = ((unsigned)u) << 16;
    return v.f;
}

// ---------------- CSR build, keyed by (relation, dst) ----------------
__global__ void k_count(const int* e0, const int* e1, const int* e2,
                        const int* e3, const int* e4, int* cnt, int E) {
    int gid = blockIdx.x * 256 + threadIdx.x;
    if (gid >= R_REL * E) return;
    int r = gid / E, e = gid - r * E;
    const int* ei = (r == 0) ? e0 : (r == 1) ? e1 : (r == 2) ? e2 : (r == 3) ? e3 : e4;
    atomicAdd(&cnt[r * N_NODES + ei[E + e]], 1);
}

__global__ __launch_bounds__(256) void k_scan1(const int* __restrict__ cnt,
                                               int* __restrict__ off, int* __restrict__ bsum) {
    __shared__ int ts[256];
    int t = threadIdx.x;
    int base = blockIdx.x * 1024 + t * 4;
    int v[4];
    #pragma unroll
    for (int j = 0; j < 4; j++) v[j] = (base + j < M5) ? cnt[base + j] : 0;
    int tsum = v[0] + v[1] + v[2] + v[3];
    ts[t] = tsum; __syncthreads();
    for (int o = 1; o < 256; o <<= 1) {
        int x = (t >= o) ? ts[t - o] : 0;
        __syncthreads();
        ts[t] += x;
        __syncthreads();
    }
    if (t == 255) bsum[blockIdx.x] = ts[255];
    int run = ts[t] - tsum;
    #pragma unroll
    for (int j = 0; j < 4; j++) { if (base + j < M5) off[base + j] = run; run += v[j]; }
}

__global__ __launch_bounds__(512) void k_scan2(int* bsum, int nblk) {
    __shared__ int ts[512];
    int t = threadIdx.x;
    int v = (t < nblk) ? bsum[t] : 0;
    ts[t] = v; __syncthreads();
    for (int o = 1; o < 512; o <<= 1) {
        int x = (t >= o) ? ts[t - o] : 0;
        __syncthreads();
        ts[t] += x;
        __syncthreads();
    }
    if (t < nblk) bsum[t] = ts[t] - v;   // exclusive
}

__global__ void k_scan3(const int* __restrict__ off, const int* __restrict__ bsum,
                        int* __restrict__ mstart, int* __restrict__ mcur,
                        const int* __restrict__ cnt, float* __restrict__ invc) {
    int i = blockIdx.x * 256 + threadIdx.x;
    if (i >= M5) return;
    int o = off[i] + bsum[i >> 10];
    mstart[i] = o;
    mcur[i] = o;
    int c = cnt[i];
    invc[i] = 1.0f / (float)max(c, 1);
    if (i == M5 - 1) mstart[M5] = o + c;
}

__global__ void k_fill(const int* e0, const int* e1, const int* e2,
                       const int* e3, const int* e4, int* mcur,
                       int* __restrict__ mrec, int E) {
    int gid = blockIdx.x * 256 + threadIdx.x;
    if (gid >= R_REL * E) return;
    int r = gid / E, e = gid - r * E;
    const int* ei = (r == 0) ? e0 : (r == 1) ? e1 : (r == 2) ? e2 : (r == 3) ? e3 : e4;
    int src = ei[e], dst = ei[E + e];
    int pos = atomicAdd(&mcur[r * N_NODES + dst], 1);
    mrec[pos] = src;
}

// ---------------- X fp32 -> bf16, padded [NPAD][192] ----------------
__global__ void k_castX(const float* __restrict__ X, unsigned short* __restrict__ Xb) {
    int gid = blockIdx.x * 256 + threadIdx.x;
    if (gid >= NPAD * KSEG0) return;
    int row = gid / KSEG0, k = gid - row * KSEG0;
    float v = (row < N_NODES && k < IN_F) ? X[(size_t)row * IN_F + k] : 0.f;
    Xb[gid] = (unsigned short)f2bf(v);
}

// ---------------- weight transpose: Wt[col][KCAT] with seg-concat K ----------------
__global__ void k_tw0(const float* __restrict__ root0, const float* __restrict__ W0,
                      short* __restrict__ out) {
    int gid = blockIdx.x * 256 + threadIdx.x;   // 128 * 1152
    if (gid >= 128 * KC0) return;
    int col = gid / KC0;
    int kk = gid - col * KC0;
    int chunk = kk / KSEG0, k = kk - chunk * KSEG0;
    float v = 0.f;
    if (k < IN_F)
        v = (chunk == 0) ? root0[k * HID + col]
                         : W0[((size_t)(chunk - 1) * IN_F + k) * HID + col];
    out[gid] = f2bf(v);
}

__global__ void k_twl(const float* __restrict__ rootl, const float* __restrict__ Wl,
                      short* __restrict__ out) {
    int gid = blockIdx.x * 256 + threadIdx.x;   // 2 * 128 * 768
    if (gid >= L_LAYERS * 128 * KC1) return;
    int l = gid / (128 * KC1);
    int rem = gid - l * 128 * KC1;
    int col = rem / KC1;
    int kk = rem - col * KC1;
    int chunk = kk / HID, k = kk - chunk * HID;
    float v = (chunk == 0) ? rootl[((size_t)l * HID + k) * HID + col]
                           : Wl[(((size_t)l * R_REL + (chunk - 1)) * HID + k) * HID + col];
    out[gid] = f2bf(v);
}

// ---------------- fused gather+GEMM ----------------
// h'[row][0:128] = relu( [A0 | Z1..Z5] @ Wt^T + bias ). Z_r rows for this block's
// 128 dsts are gathered (mean of A0[src]) straight into LDS per segment — never
// materialized in global. Gather: each 16-lane group owns one dst; CSR metadata
// (mstart/invc) and edges (mrec) loaded DIRECTLY (uniform within group, broadcast),
// 1-deep mrec prefetch to overlap index fetch with row summation. No cross-lane ops.
template<int KSEG>
__global__ __launch_bounds__(256)
void gemm_fused(const unsigned short* __restrict__ A0, const short* __restrict__ Wt,
                const float* __restrict__ bias,
                const int* __restrict__ mstart, const int* __restrict__ mrec,
                const float* __restrict__ invc,
                unsigned short* __restrict__ Hout) {
    constexpr int KS = KSEG / 32;            // k-steps per segment (6 or 4)
    constexpr int KCAT = 6 * KSEG;
    constexpr int SA = KSEG + 8;             // Z-tile LDS row stride (shorts)
    constexpr int NP = KSEG / 64;            // 8B gather passes per row (3 or 2)
    __shared__ short Zs[128 * SA];

    const int row0 = blockIdx.x * 128;
    const int tid = threadIdx.x;
    const int lane = tid & 63, wv = tid >> 6;
    const int quad = lane >> 4, l16 = lane & 15;   // also gather group / group-lane
    const int wr0 = (wv >> 1) * 64, wc0 = (wv & 1) * 64;

    const unsigned short* a0p = A0 + (size_t)(row0 + wr0 + l16) * KSEG + quad * 8;
    const short* Bp = Wt + (size_t)(wc0 + l16) * KCAT + quad * 8;

    f32x4 acc[4][4];
    #pragma unroll
    for (int i = 0; i < 4; i++)
        #pragma unroll
        for (int j = 0; j < 4; j++) acc[i][j] = (f32x4){0.f, 0.f, 0.f, 0.f};

    // ---- seg0: root term, A direct from global, 1-deep register dbuf ----
    bf16x8 ac[4], bc[4], an[4], bn[4];
    #pragma unroll
    for (int i = 0; i < 4; i++) {
        ac[i] = *(const bf16x8*)(a0p + (size_t)i * 16 * KSEG);
        bc[i] = *(const bf16x8*)(Bp + (size_t)i * 16 * KCAT);
    }
    #pragma unroll
    for (int t = 0; t < KS; t++) {
        if (t + 1 < KS) {
            #pragma unroll
            for (int i = 0; i < 4; i++) {
                an[i] = *(const bf16x8*)(a0p + (size_t)i * 16 * KSEG + (t + 1) * 32);
                bn[i] = *(const bf16x8*)(Bp + (size_t)i * 16 * KCAT + (t + 1) * 32);
            }
        }
        #pragma unroll
        for (int i = 0; i < 4; i++)
            #pragma unroll
            for (int j = 0; j < 4; j++)
                acc[i][j] = __builtin_amdgcn_mfma_f32_16x16x32_bf16(ac[i], bc[j], acc[i][j], 0, 0, 0);
        if (t + 1 < KS) {
            #pragma unroll
            for (int i = 0; i < 4; i++) { ac[i] = an[i]; bc[i] = bn[i]; }
        }
    }

    // ---- relation segments: gather into LDS, then MFMA from LDS ----
    for (int sg = 0; sg < R_REL; sg++) {
        const int tb = (1 + sg) * KS;
        // prefetch this segment's first B fragments (in flight during gather)
        #pragma unroll
        for (int j = 0; j < 4; j++)
            bc[j] = *(const bf16x8*)(Bp + (size_t)j * 16 * KCAT + tb * 32);

        const int segbase = sg * N_NODES;
        for (int bt = 0; bt < 8; bt++) {
            const int d = row0 + wv * 32 + bt * 4 + quad;   // this group's dst
            int s = 0, e = 0;
            float w = 0.f;
            if (d < N_NODES) {                 // padded dsts -> zero Z row
                s = mstart[segbase + d];
                e = mstart[segbase + d + 1];
                w = invc[segbase + d];
            }
            float s0[NP], s1[NP], s2[NP], s3[NP];
            #pragma unroll
            for (int p = 0; p < NP; p++) { s0[p] = 0.f; s1[p] = 0.f; s2[p] = 0.f; s3[p] = 0.f; }
            int srcn = (s < e) ? mrec[s] : 0;  // uniform within group (broadcast)
            for (int j = s; j < e; j++) {
                int src = srcn;
                if (j + 1 < e) srcn = mrec[j + 1];   // prefetch next edge index
                const unsigned short* row = A0 + (size_t)src * KSEG;
                #pragma unroll
                for (int p = 0; p < NP; p++) {
                    uint2 v = *(const uint2*)(row + p * 64 + l16 * 4);
                    s0[p] += bf2f((unsigned short)(v.x & 0xffff));
                    s1[p] += bf2f((unsigned short)(v.x >> 16));
                    s2[p] += bf2f((unsigned short)(v.y & 0xffff));
                    s3[p] += bf2f((unsigned short)(v.y >> 16));
                }
            }
            int dl = wv * 32 + bt * 4 + quad;
            #pragma unroll
            for (int p = 0; p < NP; p++) {
                unsigned x = (unsigned)(unsigned short)f2bf(s0[p] * w) |
                             ((unsigned)(unsigned short)f2bf(s1[p] * w) << 16);
                unsigned y = (unsigned)(unsigned short)f2bf(s2[p] * w) |
                             ((unsigned)(unsigned short)f2bf(s3[p] * w) << 16);
                uint2 pv; pv.x = x; pv.y = y;
                *(uint2*)&Zs[dl * SA + p * 64 + l16 * 4] = pv;
            }
        }
        __syncthreads();      // Z tile staged

        #pragma unroll
        for (int k = 0; k < KS; k++) {
            if (k + 1 < KS) {
                #pragma unroll
                for (int j = 0; j < 4; j++)
                    bn[j] = *(const bf16x8*)(Bp + (size_t)j * 16 * KCAT + (tb + k + 1) * 32);
            }
            #pragma unroll
            for (int i = 0; i < 4; i++)
                ac[i] = *(const bf16x8*)&Zs[(wr0 + i * 16 + l16) * SA + k * 32 + quad * 8];
            #pragma unroll
            for (int i = 0; i < 4; i++)
                #pragma unroll
                for (int j = 0; j < 4; j++)
                    acc[i][j] = __builtin_amdgcn_mfma_f32_16x16x32_bf16(ac[i], bc[j], acc[i][j], 0, 0, 0);
            if (k + 1 < KS) {
                #pragma unroll
                for (int j = 0; j < 4; j++) bc[j] = bn[j];
            }
        }
        __syncthreads();      // all waves done with Zs before next gather
    }

    // ---- fused bias + relu -> LDS (stride 136) -> coalesced bf16x8 stores ----
    float bj[4];
    #pragma unroll
    for (int j = 0; j < 4; j++) bj[j] = bias[wc0 + j * 16 + l16];
    #pragma unroll
    for (int i = 0; i < 4; i++)
        #pragma unroll
        for (int j = 0; j < 4; j++)
            #pragma unroll
            for (int reg = 0; reg < 4; reg++)
                Zs[(wr0 + i * 16 + quad * 4 + reg) * 136 + wc0 + j * 16 + l16] =
                    f2bf(fmaxf(acc[i][j][reg] + bj[j], 0.f));
    __syncthreads();

    #pragma unroll
    for (int s = 0; s < 8; s++) {
        int row = (tid >> 4) + s * 16;
        int col = (tid & 15) * 8;
        bf16x8 v = *(const bf16x8*)&Zs[row * 136 + col];
        *(bf16x8*)&Hout[(size_t)(row0 + row) * HID + col] = v;
    }
}

// ---------------- readout ----------------
__global__ __launch_bounds__(128)
void k_pool(const unsigned short* __restrict__ h, const int* __restrict__ batch,
            float* __restrict__ pooled) {
    int c = threadIdx.x;
    int start = blockIdx.x * 128;
    if (start >= N_NODES) return;
    int end = min(start + 128, N_NODES);
    int g = batch[start];
    float s = 0.f;
    for (int i = start; i < end; i++) {
        int gi = batch[i];
        if (gi != g) { atomicAdd(&pooled[g * HID + c], s); s = 0.f; g = gi; }
        s += bf2f(h[(size_t)i * HID + c]);
    }
    atomicAdd(&pooled[g * HID + c], s);
}

__device__ int lower_bound_i(const int* a, int n, int v) {
    int lo = 0, hi = n;
    while (lo < hi) {
        int mid = (lo + hi) >> 1;
        if (a[mid] < v) lo = mid + 1; else hi = mid;
    }
    return lo;
}

__global__ __launch_bounds__(128)
void k_mlp(const float* __restrict__ pooled, const int* __restrict__ batch,
           const float* __restrict__ Wc1, const float* __restrict__ bc1,
           const float* __restrict__ Wc2, const float* __restrict__ bc2,
           const float* __restrict__ Wc3, const float* __restrict__ bc3,
           float* __restrict__ out) {
    int g = blockIdx.x;
    int c = threadIdx.x;
    __shared__ int range[2];
    if (c == 0) range[0] = lower_bound_i(batch, N_NODES, g);
    if (c == 1) range[1] = lower_bound_i(batch, N_NODES, g + 1);
    __syncthreads();
    float denom = fmaxf((float)(range[1] - range[0]), 1.0f);
    __shared__ float row[HID], h1[HID], h2[HID];
    row[c] = pooled[g * HID + c] / denom;
    __syncthreads();
    float acc = bc1[c];
    for (int k = 0; k < HID; k++) acc += row[k] * Wc1[k * HID + c];
    h1[c] = fmaxf(acc, 0.f);
    __syncthreads();
    acc = bc2[c];
    for (int k = 0; k < HID; k++) acc += h1[k] * Wc2[k * HID + c];
    h2[c] = fmaxf(acc, 0.f);
    __syncthreads();
    float t = h2[c] * Wc3[c];
    for (int off = 32; off > 0; off >>= 1) t += __shfl_down(t, off, 64);
    __shared__ float part[2];
    if ((c & 63) == 0) part[c >> 6] = t;
    __syncthreads();
    if (c == 0) out[g] = part[0] + part[1] + bc3[0];
}

// ---------------- launcher ----------------
extern "C" void kernel_launch(void* const* d_in, const int* in_sizes, int n_in,
                              void* d_out, int out_size, void* d_ws, size_t ws_size,
                              hipStream_t stream) {
    const float* X     = (const float*)d_in[0];
    const int*   batch = (const int*)d_in[1];
    const int*   e0 = (const int*)d_in[2];
    const int*   e1 = (const int*)d_in[3];
    const int*   e2 = (const int*)d_in[4];
    const int*   e3 = (const int*)d_in[5];
    const int*   e4 = (const int*)d_in[6];
    const float* W0    = (const float*)d_in[7];
    const float* root0 = (const float*)d_in[8];
    const float* b0    = (const float*)d_in[9];
    const float* Wl    = (const float*)d_in[10];
    const float* rootl = (const float*)d_in[11];
    const float* bl    = (const float*)d_in[12];
    const float* Wc1   = (const float*)d_in[13];
    const float* bc1   = (const float*)d_in[14];
    const float* Wc2   = (const float*)d_in[15];
    const float* bc2   = (const float*)d_in[16];
    const float* Wc3   = (const float*)d_in[17];
    const float* bc3   = (const float*)d_in[18];
    const int E = in_sizes[2] / 2;
    const int NE = R_REL * E;

    char* base = (char*)d_ws;
    size_t o = 0;
    auto carve = [&](size_t bytes) -> char* {
        char* p = base + o;
        o = (o + bytes + 255) & ~(size_t)255;
        return p;
    };
    // No Z buffer at all: total ~75 MB.
    unsigned short* h1 = (unsigned short*)carve((size_t)NPAD * HID * 2);    // also h3
    unsigned short* Xb = (unsigned short*)carve((size_t)NPAD * KSEG0 * 2);  // also h2
    int*   cnt    = (int*)carve((size_t)M5 * 4);
    float* invc   = (float*)carve((size_t)M5 * 4);
    int*   offsc  = (int*)carve((size_t)M5 * 4);
    int*   mstart = (int*)carve((size_t)(M5 + 1) * 4);
    int*   mrec   = (int*)carve((size_t)NE * 4);
    int*   bsum   = (int*)carve(2048);
    float* pooled = (float*)carve((size_t)G_GRAPHS * HID * 4);
    short* Wt0    = (short*)carve((size_t)128 * KC0 * 2);
    short* Wtl    = (short*)carve((size_t)L_LAYERS * 128 * KC1 * 2);
    int*   mcur   = offsc;                 // offsc dead after k_scan3
    unsigned short* h2 = Xb;               // Xb dead after layer-0 GEMM

    // ---- CSR build + casts + weight transposes ----
    hipMemsetAsync(cnt, 0, (size_t)M5 * 4, stream);
    hipMemsetAsync(pooled, 0, (size_t)G_GRAPHS * HID * 4, stream);
    int eg = (NE + 255) / 256;
    k_count<<<eg, 256, 0, stream>>>(e0, e1, e2, e3, e4, cnt, E);
    int nblk = (M5 + 1023) / 1024;   // 489
    k_scan1<<<nblk, 256, 0, stream>>>(cnt, offsc, bsum);
    k_scan2<<<1, 512, 0, stream>>>(bsum, nblk);
    k_scan3<<<(M5 + 255) / 256, 256, 0, stream>>>(offsc, bsum, mstart, mcur, cnt, invc);
    k_fill<<<eg, 256, 0, stream>>>(e0, e1, e2, e3, e4, mcur, mrec, E);
    k_castX<<<(NPAD * KSEG0 + 255) / 256, 256, 0, stream>>>(X, Xb);
    k_tw0<<<(128 * KC0 + 255) / 256, 256, 0, stream>>>(root0, W0, Wt0);
    k_twl<<<(L_LAYERS * 128 * KC1 + 255) / 256, 256, 0, stream>>>(rootl, Wl, Wtl);

    // ---- three fused gather+GEMM layers ----
    gemm_fused<KSEG0><<<NTILES, 256, 0, stream>>>(Xb, Wt0, b0, mstart, mrec, invc, h1);
    gemm_fused<HID><<<NTILES, 256, 0, stream>>>(h1, Wtl, bl, mstart, mrec, invc, h2);
    gemm_fused<HID><<<NTILES, 256, 0, stream>>>(h2, Wtl + (size_t)128 * KC1, bl + HID,
                                                mstart, mrec, invc, h1);

    // ---- readout ----
    k_pool<<<(N_NODES + 127) / 128, 128, 0, stream>>>(h1, batch, pooled);
    k_mlp<<<G_GRAPHS, 128, 0, stream>>>(pooled, batch, Wc1, bc1, Wc2, bc2, Wc3, bc3, (float*)d_out);
}

// Round 8
// 752.070 us; speedup vs baseline: 1.2611x; 1.1027x over previous
//
#include <hip/hip_runtime.h>

#define N_NODES 100000
#define NPAD    100096      // 782 * 128
#define NTILES  782
#define G_GRAPHS 256
#define IN_F 162
#define HID 128
#define R_REL 5
#define L_LAYERS 2
#define M5 (R_REL * N_NODES)
#define KSEG0 192           // layer-0 segment width (162 padded to 192)
#define KC0   (6 * KSEG0)   // 1152 : logical K of layer-0 GEMM
#define KC1   (6 * HID)     // 768  : logical K of layer-1/2 GEMM

typedef __attribute__((ext_vector_type(8))) short bf16x8;
typedef __attribute__((ext_vector_type(4))) float f32x4;

__device__ __forceinline__ short f2bf(float f) {
    union { float f; unsigned u; } v; v.f = f;
    unsigned r = (v.u + 0x7fffu + ((v.u >> 16) & 1u)) >> 16;
    return (short)r;
}
__device__ __forceinline__ float bf2f(unsigned short u) {
    union { unsigned u; float f; } v; v.u = ((unsigned)u) << 16;
    return v.f;
}

// ---------------- CSR build, keyed by (relation, dst) ----------------
__global__ void k_count(const int* e0, const int* e1, const int* e2,
                        const int* e3, const int* e4, int* cnt, int E) {
    int gid = blockIdx.x * 256 + threadIdx.x;
    if (gid >= R_REL * E) return;
    int r = gid / E, e = gid - r * E;
    const int* ei = (r == 0) ? e0 : (r == 1) ? e1 : (r == 2) ? e2 : (r == 3) ? e3 : e4;
    atomicAdd(&cnt[r * N_NODES + ei[E + e]], 1);
}

__global__ __launch_bounds__(256) void k_scan1(const int* __restrict__ cnt,
                                               int* __restrict__ off, int* __restrict__ bsum) {
    __shared__ int ts[256];
    int t = threadIdx.x;
    int base = blockIdx.x * 1024 + t * 4;
    int v[4];
    #pragma unroll
    for (int j = 0; j < 4; j++) v[j] = (base + j < M5) ? cnt[base + j] : 0;
    int tsum = v[0] + v[1] + v[2] + v[3];
    ts[t] = tsum; __syncthreads();
    for (int o = 1; o < 256; o <<= 1) {
        int x = (t >= o) ? ts[t - o] : 0;
        __syncthreads();
        ts[t] += x;
        __syncthreads();
    }
    if (t == 255) bsum[blockIdx.x] = ts[255];
    int run = ts[t] - tsum;
    #pragma unroll
    for (int j = 0; j < 4; j++) { if (base + j < M5) off[base + j] = run; run += v[j]; }
}

__global__ __launch_bounds__(512) void k_scan2(int* bsum, int nblk) {
    __shared__ int ts[512];
    int t = threadIdx.x;
    int v = (t < nblk) ? bsum[t] : 0;
    ts[t] = v; __syncthreads();
    for (int o = 1; o < 512; o <<= 1) {
        int x = (t >= o) ? ts[t - o] : 0;
        __syncthreads();
        ts[t] += x;
        __syncthreads();
    }
    if (t < nblk) bsum[t] = ts[t] - v;   // exclusive
}

__global__ void k_scan3(const int* __restrict__ off, const int* __restrict__ bsum,
                        int* __restrict__ mstart, int* __restrict__ mcur,
                        const int* __restrict__ cnt, float* __restrict__ invc) {
    int i = blockIdx.x * 256 + threadIdx.x;
    if (i >= M5) return;
    int o = off[i] + bsum[i >> 10];
    mstart[i] = o;
    mcur[i] = o;
    int c = cnt[i];
    invc[i] = 1.0f / (float)max(c, 1);
    if (i == M5 - 1) mstart[M5] = o + c;
}

__global__ void k_fill(const int* e0, const int* e1, const int* e2,
                       const int* e3, const int* e4, int* mcur,
                       int* __restrict__ mrec, int E) {
    int gid = blockIdx.x * 256 + threadIdx.x;
    if (gid >= R_REL * E) return;
    int r = gid / E, e = gid - r * E;
    const int* ei = (r == 0) ? e0 : (r == 1) ? e1 : (r == 2) ? e2 : (r == 3) ? e3 : e4;
    int src = ei[e], dst = ei[E + e];
    int pos = atomicAdd(&mcur[r * N_NODES + dst], 1);
    mrec[pos] = src;
}

// ---------------- X fp32 -> bf16, padded [NPAD][192] ----------------
__global__ void k_castX(const float* __restrict__ X, unsigned short* __restrict__ Xb) {
    int gid = blockIdx.x * 256 + threadIdx.x;
    if (gid >= NPAD * KSEG0) return;
    int row = gid / KSEG0, k = gid - row * KSEG0;
    float v = (row < N_NODES && k < IN_F) ? X[(size_t)row * IN_F + k] : 0.f;
    Xb[gid] = (unsigned short)f2bf(v);
}

// ---------------- weight transpose: Wt[col][KCAT] with seg-concat K ----------------
__global__ void k_tw0(const float* __restrict__ root0, const float* __restrict__ W0,
                      short* __restrict__ out) {
    int gid = blockIdx.x * 256 + threadIdx.x;   // 128 * 1152
    if (gid >= 128 * KC0) return;
    int col = gid / KC0;
    int kk = gid - col * KC0;
    int chunk = kk / KSEG0, k = kk - chunk * KSEG0;
    float v = 0.f;
    if (k < IN_F)
        v = (chunk == 0) ? root0[k * HID + col]
                         : W0[((size_t)(chunk - 1) * IN_F + k) * HID + col];
    out[gid] = f2bf(v);
}

__global__ void k_twl(const float* __restrict__ rootl, const float* __restrict__ Wl,
                      short* __restrict__ out) {
    int gid = blockIdx.x * 256 + threadIdx.x;   // 2 * 128 * 768
    if (gid >= L_LAYERS * 128 * KC1) return;
    int l = gid / (128 * KC1);
    int rem = gid - l * 128 * KC1;
    int col = rem / KC1;
    int kk = rem - col * KC1;
    int chunk = kk / HID, k = kk - chunk * HID;
    float v = (chunk == 0) ? rootl[((size_t)l * HID + k) * HID + col]
                           : Wl[(((size_t)l * R_REL + (chunk - 1)) * HID + k) * HID + col];
    out[gid] = f2bf(v);
}

// ---------------- fused gather+GEMM, latency-hidden gather ----------------
// h'[row][0:128] = relu( [A0 | Z1..Z5] @ Wt^T + bias ). Z never hits global.
// Latency plan: block-cooperative staging of CSR meta (mstart/invc slices) and
// per-segment edge indices (mrec run is contiguous per block) into LDS, so the
// only latency op left in the per-group chain is the 256-384B row gather itself,
// walked as a flat per-group edge stream (8 consecutive dsts/group) with 2-deep
// row prefetch and LDS-scalar boundary flush (no runtime-indexed reg arrays).
template<int KSEG>
__global__ __launch_bounds__(256)
void gemm_fused(const unsigned short* __restrict__ A0, const short* __restrict__ Wt,
                const float* __restrict__ bias,
                const int* __restrict__ mstart, const int* __restrict__ mrec,
                const float* __restrict__ invc,
                unsigned short* __restrict__ Hout) {
    constexpr int KS = KSEG / 32;                 // k-steps per segment (6 or 4)
    constexpr int KCAT = 6 * KSEG;
    constexpr int SA = (KSEG == 192) ? 184 : 136; // Z-tile LDS row stride (shorts)
    constexpr int NP = KSEG / 64;                 // 8B gather passes per row (3 or 2)
    constexpr int EBUF = 512;                     // staged edge indices per segment
    __shared__ short Zs[128 * SA + 16];           // +16: k=5 quad=3 read spills 8 shorts
    __shared__ int   sMS[5 * 129];                // mstart slices (block dsts, 5 segs)
    __shared__ float sMW[5 * 128];                // invc slices
    __shared__ int   sE[EBUF];                    // per-segment edge indices

    const int row0 = blockIdx.x * 128;
    const int tid = threadIdx.x;
    const int lane = tid & 63, wv = tid >> 6;
    const int quad = lane >> 4, l16 = lane & 15;
    const int wr0 = (wv >> 1) * 64, wc0 = (wv & 1) * 64;
    const int local0 = wv * 32 + quad * 8;        // this group's first dst (8 consecutive)

    // ---- stage CSR meta for the whole block (overlaps seg0 MFMA) ----
    for (int i = tid; i < 5 * 129; i += 256) {
        int seg = i / 129, o = i - seg * 129;
        sMS[i] = mstart[seg * N_NODES + min(row0 + o, N_NODES)];
    }
    for (int i = tid; i < 5 * 128; i += 256) {
        int seg = i >> 7, o = i & 127;
        int d = row0 + o;
        sMW[i] = (d < N_NODES) ? invc[seg * N_NODES + d] : 0.f;
    }

    const unsigned short* a0p = A0 + (size_t)(row0 + wr0 + l16) * KSEG + quad * 8;
    const short* Bp = Wt + (size_t)(wc0 + l16) * KCAT + quad * 8;

    f32x4 acc[4][4];
    #pragma unroll
    for (int i = 0; i < 4; i++)
        #pragma unroll
        for (int j = 0; j < 4; j++) acc[i][j] = (f32x4){0.f, 0.f, 0.f, 0.f};

    // ---- seg0: root term, A direct from global, 1-deep register dbuf ----
    bf16x8 ac[4], bc[4], an[4], bn[4];
    #pragma unroll
    for (int i = 0; i < 4; i++) {
        ac[i] = *(const bf16x8*)(a0p + (size_t)i * 16 * KSEG);
        bc[i] = *(const bf16x8*)(Bp + (size_t)i * 16 * KCAT);
    }
    #pragma unroll
    for (int t = 0; t < KS; t++) {
        if (t + 1 < KS) {
            #pragma unroll
            for (int i = 0; i < 4; i++) {
                an[i] = *(const bf16x8*)(a0p + (size_t)i * 16 * KSEG + (t + 1) * 32);
                bn[i] = *(const bf16x8*)(Bp + (size_t)i * 16 * KCAT + (t + 1) * 32);
            }
        }
        #pragma unroll
        for (int i = 0; i < 4; i++)
            #pragma unroll
            for (int j = 0; j < 4; j++)
                acc[i][j] = __builtin_amdgcn_mfma_f32_16x16x32_bf16(ac[i], bc[j], acc[i][j], 0, 0, 0);
        if (t + 1 < KS) {
            #pragma unroll
            for (int i = 0; i < 4; i++) { ac[i] = an[i]; bc[i] = bn[i]; }
        }
    }
    __syncthreads();   // meta staged + visible before first sE stage reads sMS

    // ---- relation segments ----
    for (int sg = 0; sg < R_REL; sg++) {
        const int tb = (1 + sg) * KS;
        // prefetch this segment's first B fragments (in flight during gather)
        #pragma unroll
        for (int j = 0; j < 4; j++)
            bc[j] = *(const bf16x8*)(Bp + (size_t)j * 16 * KCAT + tb * 32);

        // stage this segment's edge-index run (contiguous in mrec) into LDS
        const int blo = sMS[sg * 129];
        {
            int cnt = sMS[sg * 129 + 128] - blo;
            if (cnt > EBUF) cnt = EBUF;
            for (int i = tid; i < cnt; i += 256) sE[i] = mrec[blo + i];
        }
        __syncthreads();   // sE ready; prior MFMA done reading Zs

        // ---- gather: flat edge walk over 8 consecutive dsts per group ----
        {
            const int jlo = sMS[sg * 129 + local0];
            const int jhi = sMS[sg * 129 + local0 + 8];
            int di = 0;
            int nextb = sMS[sg * 129 + local0 + 1];
            float a0[NP], a1[NP], a2[NP], a3[NP];
            #pragma unroll
            for (int p = 0; p < NP; p++) { a0[p] = 0.f; a1[p] = 0.f; a2[p] = 0.f; a3[p] = 0.f; }
            uint2 v0[NP], v1[NP];
            if (jlo < jhi) {
                int jj = jlo - blo;
                int src = (jj < EBUF) ? sE[jj] : mrec[jlo];
                const unsigned short* r = A0 + (size_t)src * KSEG;
                #pragma unroll
                for (int p = 0; p < NP; p++) v0[p] = *(const uint2*)(r + p * 64 + l16 * 4);
            }
            if (jlo + 1 < jhi) {
                int jj = jlo + 1 - blo;
                int src = (jj < EBUF) ? sE[jj] : mrec[jlo + 1];
                const unsigned short* r = A0 + (size_t)src * KSEG;
                #pragma unroll
                for (int p = 0; p < NP; p++) v1[p] = *(const uint2*)(r + p * 64 + l16 * 4);
            }
            for (int j = jlo; ; j++) {
                while (di < 8 && j == nextb) {      // flush dst(s) ending here
                    float w = sMW[sg * 128 + local0 + di];
                    int zr = (local0 + di) * SA;
                    #pragma unroll
                    for (int p = 0; p < NP; p++) {
                        unsigned x = (unsigned)(unsigned short)f2bf(a0[p] * w) |
                                     ((unsigned)(unsigned short)f2bf(a1[p] * w) << 16);
                        unsigned y = (unsigned)(unsigned short)f2bf(a2[p] * w) |
                                     ((unsigned)(unsigned short)f2bf(a3[p] * w) << 16);
                        uint2 pv; pv.x = x; pv.y = y;
                        if (p < 2 || l16 < 10)      // layer0 p=2: packed cols 128..167
                            *(uint2*)&Zs[zr + p * 64 + l16 * 4] = pv;
                        a0[p] = 0.f; a1[p] = 0.f; a2[p] = 0.f; a3[p] = 0.f;
                    }
                    di++;
                    nextb = (di < 8) ? sMS[sg * 129 + local0 + di + 1] : 0x7fffffff;
                }
                if (j >= jhi) break;
                #pragma unroll
                for (int p = 0; p < NP; p++) {
                    a0[p] += bf2f((unsigned short)(v0[p].x & 0xffff));
                    a1[p] += bf2f((unsigned short)(v0[p].x >> 16));
                    a2[p] += bf2f((unsigned short)(v0[p].y & 0xffff));
                    a3[p] += bf2f((unsigned short)(v0[p].y >> 16));
                }
                #pragma unroll
                for (int p = 0; p < NP; p++) v0[p] = v1[p];
                if (j + 2 < jhi) {
                    int jj = j + 2 - blo;
                    int src = (jj < EBUF) ? sE[jj] : mrec[j + 2];
                    const unsigned short* r = A0 + (size_t)src * KSEG;
                    #pragma unroll
                    for (int p = 0; p < NP; p++) v1[p] = *(const uint2*)(r + p * 64 + l16 * 4);
                }
            }
        }
        __syncthreads();      // Z tile staged

        // ---- MFMA from Zs (cols >= packed width have zero weights) ----
        #pragma unroll
        for (int k = 0; k < KS; k++) {
            if (k + 1 < KS) {
                #pragma unroll
                for (int j = 0; j < 4; j++)
                    bn[j] = *(const bf16x8*)(Bp + (size_t)j * 16 * KCAT + (tb + k + 1) * 32);
            }
            #pragma unroll
            for (int i = 0; i < 4; i++)
                ac[i] = *(const bf16x8*)&Zs[(wr0 + i * 16 + l16) * SA + k * 32 + quad * 8];
            #pragma unroll
            for (int i = 0; i < 4; i++)
                #pragma unroll
                for (int j = 0; j < 4; j++)
                    acc[i][j] = __builtin_amdgcn_mfma_f32_16x16x32_bf16(ac[i], bc[j], acc[i][j], 0, 0, 0);
            if (k + 1 < KS) {
                #pragma unroll
                for (int j = 0; j < 4; j++) bc[j] = bn[j];
            }
        }
    }
    __syncthreads();          // all waves done reading Zs before epilogue reuse

    // ---- fused bias + relu -> LDS (stride 136) -> coalesced bf16x8 stores ----
    float bj[4];
    #pragma unroll
    for (int j = 0; j < 4; j++) bj[j] = bias[wc0 + j * 16 + l16];
    #pragma unroll
    for (int i = 0; i < 4; i++)
        #pragma unroll
        for (int j = 0; j < 4; j++)
            #pragma unroll
            for (int reg = 0; reg < 4; reg++)
                Zs[(wr0 + i * 16 + quad * 4 + reg) * 136 + wc0 + j * 16 + l16] =
                    f2bf(fmaxf(acc[i][j][reg] + bj[j], 0.f));
    __syncthreads();

    #pragma unroll
    for (int s = 0; s < 8; s++) {
        int row = (tid >> 4) + s * 16;
        int col = (tid & 15) * 8;
        bf16x8 v = *(const bf16x8*)&Zs[row * 136 + col];
        *(bf16x8*)&Hout[(size_t)(row0 + row) * HID + col] = v;
    }
}

// ---------------- readout ----------------
__global__ __launch_bounds__(128)
void k_pool(const unsigned short* __restrict__ h, const int* __restrict__ batch,
            float* __restrict__ pooled) {
    int c = threadIdx.x;
    int start = blockIdx.x * 128;
    if (start >= N_NODES) return;
    int end = min(start + 128, N_NODES);
    int g = batch[start];
    float s = 0.f;
    for (int i = start; i < end; i++) {
        int gi = batch[i];
        if (gi != g) { atomicAdd(&pooled[g * HID + c], s); s = 0.f; g = gi; }
        s += bf2f(h[(size_t)i * HID + c]);
    }
    atomicAdd(&pooled[g * HID + c], s);
}

__device__ int lower_bound_i(const int* a, int n, int v) {
    int lo = 0, hi = n;
    while (lo < hi) {
        int mid = (lo + hi) >> 1;
        if (a[mid] < v) lo = mid + 1; else hi = mid;
    }
    return lo;
}

__global__ __launch_bounds__(128)
void k_mlp(const float* __restrict__ pooled, const int* __restrict__ batch,
           const float* __restrict__ Wc1, const float* __restrict__ bc1,
           const float* __restrict__ Wc2, const float* __restrict__ bc2,
           const float* __restrict__ Wc3, const float* __restrict__ bc3,
           float* __restrict__ out) {
    int g = blockIdx.x;
    int c = threadIdx.x;
    __shared__ int range[2];
    if (c == 0) range[0] = lower_bound_i(batch, N_NODES, g);
    if (c == 1) range[1] = lower_bound_i(batch, N_NODES, g + 1);
    __syncthreads();
    float denom = fmaxf((float)(range[1] - range[0]), 1.0f);
    __shared__ float row[HID], h1[HID], h2[HID];
    row[c] = pooled[g * HID + c] / denom;
    __syncthreads();
    float acc = bc1[c];
    for (int k = 0; k < HID; k++) acc += row[k] * Wc1[k * HID + c];
    h1[c] = fmaxf(acc, 0.f);
    __syncthreads();
    acc = bc2[c];
    for (int k = 0; k < HID; k++) acc += h1[k] * Wc2[k * HID + c];
    h2[c] = fmaxf(acc, 0.f);
    __syncthreads();
    float t = h2[c] * Wc3[c];
    for (int off = 32; off > 0; off >>= 1) t += __shfl_down(t, off, 64);
    __shared__ float part[2];
    if ((c & 63) == 0) part[c >> 6] = t;
    __syncthreads();
    if (c == 0) out[g] = part[0] + part[1] + bc3[0];
}

// ---------------- launcher ----------------
extern "C" void kernel_launch(void* const* d_in, const int* in_sizes, int n_in,
                              void* d_out, int out_size, void* d_ws, size_t ws_size,
                              hipStream_t stream) {
    const float* X     = (const float*)d_in[0];
    const int*   batch = (const int*)d_in[1];
    const int*   e0 = (const int*)d_in[2];
    const int*   e1 = (const int*)d_in[3];
    const int*   e2 = (const int*)d_in[4];
    const int*   e3 = (const int*)d_in[5];
    const int*   e4 = (const int*)d_in[6];
    const float* W0    = (const float*)d_in[7];
    const float* root0 = (const float*)d_in[8];
    const float* b0    = (const float*)d_in[9];
    const float* Wl    = (const float*)d_in[10];
    const float* rootl = (const float*)d_in[11];
    const float* bl    = (const float*)d_in[12];
    const float* Wc1   = (const float*)d_in[13];
    const float* bc1   = (const float*)d_in[14];
    const float* Wc2   = (const float*)d_in[15];
    const float* bc2   = (const float*)d_in[16];
    const float* Wc3   = (const float*)d_in[17];
    const float* bc3   = (const float*)d_in[18];
    const int E = in_sizes[2] / 2;
    const int NE = R_REL * E;

    char* base = (char*)d_ws;
    size_t o = 0;
    auto carve = [&](size_t bytes) -> char* {
        char* p = base + o;
        o = (o + bytes + 255) & ~(size_t)255;
        return p;
    };
    // No Z buffer at all: total ~75 MB.
    unsigned short* h1 = (unsigned short*)carve((size_t)NPAD * HID * 2);    // also h3
    unsigned short* Xb = (unsigned short*)carve((size_t)NPAD * KSEG0 * 2);  // also h2
    int*   cnt    = (int*)carve((size_t)M5 * 4);
    float* invc   = (float*)carve((size_t)M5 * 4);
    int*   offsc  = (int*)carve((size_t)M5 * 4);
    int*   mstart = (int*)carve((size_t)(M5 + 1) * 4);
    int*   mrec   = (int*)carve((size_t)NE * 4);
    int*   bsum   = (int*)carve(2048);
    float* pooled = (float*)carve((size_t)G_GRAPHS * HID * 4);
    short* Wt0    = (short*)carve((size_t)128 * KC0 * 2);
    short* Wtl    = (short*)carve((size_t)L_LAYERS * 128 * KC1 * 2);
    int*   mcur   = offsc;                 // offsc dead after k_scan3
    unsigned short* h2 = Xb;               // Xb dead after layer-0 GEMM

    // ---- CSR build + casts + weight transposes ----
    hipMemsetAsync(cnt, 0, (size_t)M5 * 4, stream);
    hipMemsetAsync(pooled, 0, (size_t)G_GRAPHS * HID * 4, stream);
    int eg = (NE + 255) / 256;
    k_count<<<eg, 256, 0, stream>>>(e0, e1, e2, e3, e4, cnt, E);
    int nblk = (M5 + 1023) / 1024;   // 489
    k_scan1<<<nblk, 256, 0, stream>>>(cnt, offsc, bsum);
    k_scan2<<<1, 512, 0, stream>>>(bsum, nblk);
    k_scan3<<<(M5 + 255) / 256, 256, 0, stream>>>(offsc, bsum, mstart, mcur, cnt, invc);
    k_fill<<<eg, 256, 0, stream>>>(e0, e1, e2, e3, e4, mcur, mrec, E);
    k_castX<<<(NPAD * KSEG0 + 255) / 256, 256, 0, stream>>>(X, Xb);
    k_tw0<<<(128 * KC0 + 255) / 256, 256, 0, stream>>>(root0, W0, Wt0);
    k_twl<<<(L_LAYERS * 128 * KC1 + 255) / 256, 256, 0, stream>>>(rootl, Wl, Wtl);

    // ---- three fused gather+GEMM layers ----
    gemm_fused<KSEG0><<<NTILES, 256, 0, stream>>>(Xb, Wt0, b0, mstart, mrec, invc, h1);
    gemm_fused<HID><<<NTILES, 256, 0, stream>>>(h1, Wtl, bl, mstart, mrec, invc, h2);
    gemm_fused<HID><<<NTILES, 256, 0, stream>>>(h2, Wtl + (size_t)128 * KC1, bl + HID,
                                                mstart, mrec, invc, h1);

    // ---- readout ----
    k_pool<<<(N_NODES + 127) / 128, 128, 0, stream>>>(h1, batch, pooled);
    k_mlp<<<G_GRAPHS, 128, 0, stream>>>(pooled, batch, Wc1, bc1, Wc2, bc2, Wc3, bc3, (float*)d_out);
}